// Round 5
// baseline (983.274 us; speedup 1.0000x reference)
//
#include <hip/hip_runtime.h>
#include <hip/hip_bf16.h>
#include <math.h>

// NeuroSAT RNN forward on MI355X — MFMA bf16x3, XCD-chunked gather locality.
namespace {
constexpr int NVARS    = 256;
constexpr int LITS_PER = 2 * NVARS;     // 512
constexpr int Bg       = 64;            // graphs
constexpr int NL       = Bg * LITS_PER; // 32768 literals
constexpr int CLS_PER  = 1024;
constexpr int NC       = Bg * CLS_PER;  // 65536 clauses
constexpr int NE       = NC * 3;        // 196608 edges (K=3)
constexpr int D        = 128;
constexpr int T        = 8;             // num_iters (fixed scalar input)

// d_out flat layout (reference tuple order)
constexpr size_t OFF_VOTE  = 0;                                  // [NL]
constexpr size_t OFF_XL    = (size_t)NL;                         // [NL*D]   (x_l state)
constexpr size_t OFF_POOL  = OFF_XL + (size_t)NL * D;            // [Bg]
constexpr size_t OFF_TLAST = OFF_POOL + Bg;                      // [NL]
constexpr size_t OFF_TALL  = OFF_TLAST + NL;                     // [(T+1)*NL]
constexpr size_t OFF_CALL  = OFF_TALL + (size_t)(T + 1) * NL;    // [(T+1)*NC*D] (x_c state)
constexpr size_t OFF_T0    = OFF_CALL + (size_t)(T + 1) * NC * D;// [NL]

// packed-W fragment pool (ushorts): per matrix [n][ks][lane][8], hi plane then lo plane
constexpr int PK_DD   = 8 * 4 * 64 * 8;   // D x D matrices   (16384)
constexpr int PK_D2   = 8 * 8 * 64 * 8;   // D x 2D matrix    (32768)
constexpr int O_IHLC  = 0;
constexpr int O_HHLC  = 2 * PK_DD;
constexpr int O_HHCL  = 4 * PK_DD;
constexpr int O_IHCL  = 6 * PK_DD;
constexpr int PK_TOT  = 6 * PK_DD + 2 * PK_D2;  // 163840
} // namespace

typedef __attribute__((ext_vector_type(8))) short short8v;  // 8 bf16 (4 VGPRs)
typedef __attribute__((ext_vector_type(4))) float f32x4;

__device__ __forceinline__ unsigned short f2bf(float v) {
    unsigned u = __float_as_uint(v);
    return (unsigned short)((u + 0x7fffu + ((u >> 16) & 1u)) >> 16);  // RNE
}
__device__ __forceinline__ float bf2f(unsigned short b) {
    return __uint_as_float(((unsigned)b) << 16);
}
// HW bf16 convert path (compiler emits v_cvt_pk_bf16_f32 for pairs)
__device__ __forceinline__ void cvt_frag(const float (&v)[8], short8v& ah, short8v& al) {
    #pragma unroll
    for (int j = 0; j < 8; j++) {
        unsigned short h = __builtin_bit_cast(unsigned short, __float2bfloat16(v[j]));
        ah[j] = (short)h;
        float lo = v[j] - __uint_as_float(((unsigned)h) << 16);
        al[j] = (short)__builtin_bit_cast(unsigned short, __float2bfloat16(lo));
    }
}
// acc += A*(Bhi+Blo) with A split hi/lo: 3 MFMAs (bf16x3; ~1e-5 rel err)
__device__ __forceinline__ void mm3(f32x4& c, short8v ah, short8v al,
                                    const unsigned short* __restrict__ hp,
                                    const unsigned short* __restrict__ lp, int off) {
    short8v bh = *(const short8v*)(hp + off);
    short8v bl = *(const short8v*)(lp + off);
    c = __builtin_amdgcn_mfma_f32_16x16x32_bf16(ah, bh, c, 0, 0, 0);
    c = __builtin_amdgcn_mfma_f32_16x16x32_bf16(ah, bl, c, 0, 0, 0);
    c = __builtin_amdgcn_mfma_f32_16x16x32_bf16(al, bh, c, 0, 0, 0);
}
// fast tanh: 1 - 2/(2^(2x*log2e)+1)
__device__ __forceinline__ float ftanh(float x) {
    float e = __builtin_amdgcn_exp2f(x * 2.885390081777926814f);
    return 1.0f - 2.0f * __builtin_amdgcn_rcpf(e + 1.0f);
}

// ---------------- W packing (all 4 matrices, one kernel) ---------------------
__global__ __launch_bounds__(256) void pack_all(
    const float* __restrict__ w_ihlc, const float* __restrict__ w_hhlc,
    const float* __restrict__ w_hhcl, const float* __restrict__ w_ihcl,
    unsigned short* __restrict__ pk) {
    int idx = blockIdx.x * 256 + threadIdx.x;
    const float* W; int kdim, ksteps, rel; unsigned short *hi, *lo;
    if (idx < PK_DD)          { W = w_ihlc; kdim = D;     ksteps = 4; rel = idx;             hi = pk + O_IHLC; lo = hi + PK_DD; }
    else if (idx < 2 * PK_DD) { W = w_hhlc; kdim = D;     ksteps = 4; rel = idx - PK_DD;     hi = pk + O_HHLC; lo = hi + PK_DD; }
    else if (idx < 3 * PK_DD) { W = w_hhcl; kdim = D;     ksteps = 4; rel = idx - 2 * PK_DD; hi = pk + O_HHCL; lo = hi + PK_DD; }
    else                      { W = w_ihcl; kdim = 2 * D; ksteps = 8; rel = idx - 3 * PK_DD; hi = pk + O_IHCL; lo = hi + PK_D2; }
    int j = rel & 7, lane = (rel >> 3) & 63, ks = (rel >> 9) % ksteps, n = (rel >> 9) / ksteps;
    int r = n * 16 + (lane & 15);
    int k = ks * 32 + (lane >> 4) * 8 + j;
    float w = W[(size_t)r * kdim + k];
    unsigned short h = f2bf(w);
    hi[rel] = h;
    lo[rel] = f2bf(w - bf2f(h));
}

// ---------------- CSR build (edge_lit -> literal-indexed adjacency) ----------
__global__ void csr_count(const int* __restrict__ edge_lit, int* __restrict__ counts) {
    int e = blockIdx.x * blockDim.x + threadIdx.x;
    if (e < NE) atomicAdd(&counts[edge_lit[e]], 1);
}

__global__ __launch_bounds__(1024) void csr_scan(const int* __restrict__ counts,
                                                 int* __restrict__ offs,
                                                 int* __restrict__ cursor) {
    __shared__ int part[1024];
    const int t = threadIdx.x;
    const int base = t * 32;
    int local[32];
    int s = 0;
    for (int i = 0; i < 32; i++) { local[i] = s; s += counts[base + i]; }
    part[t] = s;
    __syncthreads();
    for (int d = 1; d < 1024; d <<= 1) {
        int v = 0;
        if (t >= d) v = part[t - d];
        __syncthreads();
        if (t >= d) part[t] += v;
        __syncthreads();
    }
    const int excl = (t == 0) ? 0 : part[t - 1];
    for (int i = 0; i < 32; i++) {
        int o = excl + local[i];
        offs[base + i] = o;
        cursor[base + i] = o;
    }
    if (t == 1023) offs[NL] = part[1023];
}

__global__ void csr_fill(const int* __restrict__ edge_lit, int* __restrict__ cursor,
                         int* __restrict__ csr) {
    int e = blockIdx.x * blockDim.x + threadIdx.x;
    if (e < NE) {
        int l = edge_lit[e];
        int p = atomicAdd(&cursor[l], 1);
        csr[p] = e / 3;
    }
}

__global__ void csr_sort(const int* __restrict__ offs, int* __restrict__ csr) {
    int l = blockIdx.x * blockDim.x + threadIdx.x;
    if (l >= NL) return;
    int s = offs[l], e = offs[l + 1];
    for (int i = s + 1; i < e; i++) {
        int v = csr[i];
        int j = i - 1;
        while (j >= s && csr[j] > v) { csr[j + 1] = csr[j]; j--; }
        csr[j + 1] = v;
    }
}

// ---------------- init: row L2-normalize (+ fused dot) -----------------------
__global__ void rownorm_dot(const float* __restrict__ in, float* __restrict__ out,
                            const float* __restrict__ dotw, float* __restrict__ dot0,
                            float* __restrict__ dot1, int nrows) {
    int wave = (int)((blockIdx.x * blockDim.x + threadIdx.x) >> 6);
    int lane = threadIdx.x & 63;
    if (wave >= nrows) return;
    const float* r = in + (size_t)wave * D;
    float v0 = r[lane], v1 = r[lane + 64];
    float ss = v0 * v0 + v1 * v1;
    #pragma unroll
    for (int m = 32; m; m >>= 1) ss += __shfl_xor(ss, m);
    float rn = 1.0f / sqrtf(ss);
    float y0 = v0 * rn, y1 = v1 * rn;
    float* o = out + (size_t)wave * D;
    o[lane] = y0;
    o[lane + 64] = y1;
    if (dotw) {
        float dv = y0 * dotw[lane] + y1 * dotw[lane + 64];
        #pragma unroll
        for (int m = 32; m; m >>= 1) dv += __shfl_xor(dv, m);
        if (lane == 0) {
            dot0[wave] = dv;
            if (dot1) dot1[wave] = dv;
        }
    }
}

// ---------------- LC: xc = tanh(msg@Wih^T + xc@Whh^T + b); writes norm+scale --
// Chunked XCD swizzle: each XCD owns 8 consecutive graphs -> gather slice L2-resident.
__global__ __launch_bounds__(256, 3) void lc_mfma(
    const int* __restrict__ edge_lit, const float* __restrict__ xl,
    const float* __restrict__ xc_prev, const unsigned short* __restrict__ pk,
    const float* __restrict__ bih, const float* __restrict__ bhh,
    float* __restrict__ xc_norm, float* __restrict__ norms) {
    const int p = blockIdx.x;
    const int blk = (p & 7) * (NC / 64 / 8) + (p >> 3);   // graph-chunked per XCD
    const int tid = threadIdx.x;
    const int wid = tid >> 6, lane = tid & 63;
    const int m = lane & 15, g = lane >> 4;
    const int arow = blk * 64 + wid * 16 + m;
    const unsigned short* ih_hi = pk + O_IHLC; const unsigned short* ih_lo = ih_hi + PK_DD;
    const unsigned short* hh_hi = pk + O_HHLC; const unsigned short* hh_lo = hh_hi + PK_DD;

    f32x4 acc[8];
    #pragma unroll
    for (int n = 0; n < 8; n++) acc[n] = (f32x4)0.f;

    const int e0 = edge_lit[3 * arow], e1 = edge_lit[3 * arow + 1], e2 = edge_lit[3 * arow + 2];
    const float* r0 = xl + (size_t)e0 * D + g * 8;
    const float* r1 = xl + (size_t)e1 * D + g * 8;
    const float* r2 = xl + (size_t)e2 * D + g * 8;
    const float* rh = xc_prev + (size_t)arow * D + g * 8;

    // hidden loads first (longest latency tolerance), then gather+sum
    float vh[4][8];
    #pragma unroll
    for (int ks = 0; ks < 4; ks++) {
        float4 h0 = *(const float4*)(rh + ks * 32), h1 = *(const float4*)(rh + ks * 32 + 4);
        vh[ks][0] = h0.x; vh[ks][1] = h0.y; vh[ks][2] = h0.z; vh[ks][3] = h0.w;
        vh[ks][4] = h1.x; vh[ks][5] = h1.y; vh[ks][6] = h1.z; vh[ks][7] = h1.w;
    }
    float v[4][8];
    #pragma unroll
    for (int ks = 0; ks < 4; ks++) {
        float4 a0 = *(const float4*)(r0 + ks * 32), a1 = *(const float4*)(r0 + ks * 32 + 4);
        float4 b0 = *(const float4*)(r1 + ks * 32), b1 = *(const float4*)(r1 + ks * 32 + 4);
        float4 c0 = *(const float4*)(r2 + ks * 32), c1 = *(const float4*)(r2 + ks * 32 + 4);
        v[ks][0] = a0.x + b0.x + c0.x; v[ks][1] = a0.y + b0.y + c0.y;
        v[ks][2] = a0.z + b0.z + c0.z; v[ks][3] = a0.w + b0.w + c0.w;
        v[ks][4] = a1.x + b1.x + c1.x; v[ks][5] = a1.y + b1.y + c1.y;
        v[ks][6] = a1.z + b1.z + c1.z; v[ks][7] = a1.w + b1.w + c1.w;
    }
    #pragma unroll
    for (int ks = 0; ks < 4; ks++) {
        short8v ah, al;
        cvt_frag(v[ks], ah, al);
        #pragma unroll
        for (int n = 0; n < 8; n++) mm3(acc[n], ah, al, ih_hi, ih_lo, ((n * 4 + ks) * 64 + lane) * 8);
    }
    #pragma unroll
    for (int ks = 0; ks < 4; ks++) {
        short8v ah, al;
        cvt_frag(vh[ks], ah, al);
        #pragma unroll
        for (int n = 0; n < 8; n++) mm3(acc[n], ah, al, hh_hi, hh_lo, ((n * 4 + ks) * 64 + lane) * 8);
    }

    float bias[8];
    #pragma unroll
    for (int n = 0; n < 8; n++) bias[n] = bih[n * 16 + m] + bhh[n * 16 + m];

    const int obase = blk * 64 + wid * 16 + g * 4;  // C rows: (lane>>4)*4+r
    #pragma unroll
    for (int r = 0; r < 4; r++) {
        float w[8], ss = 0.f;
        #pragma unroll
        for (int n = 0; n < 8; n++) { w[n] = ftanh(acc[n][r] + bias[n]); ss += w[n] * w[n]; }
        ss += __shfl_xor(ss, 1); ss += __shfl_xor(ss, 2);
        ss += __shfl_xor(ss, 4); ss += __shfl_xor(ss, 8);
        const float rn = __builtin_amdgcn_rsqf(ss);
        const size_t rowoff = (size_t)(obase + r) * D + m;
        #pragma unroll
        for (int n = 0; n < 8; n++) xc_norm[rowoff + n * 16] = w[n] * rn;
        if (m == 0) norms[obase + r] = ss * rn;  // = ||row|| (pre-norm scale for CL gather)
    }
}

// -------- CL: xl = tanh([msg,flip]@Wih^T + xl@Whh^T + b); norm+truth(+vote) --
__global__ __launch_bounds__(256, 3) void cl_mfma(
    const int* __restrict__ offs, const int* __restrict__ csr,
    const float* __restrict__ xc_norm, const float* __restrict__ norms,
    const float* __restrict__ xl, const unsigned short* __restrict__ pk,
    const float* __restrict__ bih, const float* __restrict__ bhh,
    const float* __restrict__ tv, const float* __restrict__ vw,
    const float* __restrict__ vb,
    float* __restrict__ xl_out, float* __restrict__ truth,
    float* __restrict__ truth2, float* __restrict__ vote) {
    const int p0 = blockIdx.x;
    const int blk = (p0 & 7) * (NL / 64 / 8) + (p0 >> 3);  // graph-chunked per XCD
    const int tid = threadIdx.x;
    const int wid = tid >> 6, lane = tid & 63;
    const int m = lane & 15, g = lane >> 4;
    const int arow = blk * 64 + wid * 16 + m;
    const unsigned short* ih_hi = pk + O_IHCL; const unsigned short* ih_lo = ih_hi + PK_D2;
    const unsigned short* hh_hi = pk + O_HHCL; const unsigned short* hh_lo = hh_hi + PK_DD;

    f32x4 acc[8];
    #pragma unroll
    for (int n = 0; n < 8; n++) acc[n] = (f32x4)0.f;

    // msg gather: Σ norms[c]*xc_norm[c]; 2-way ILP (even/odd p)
    float v[4][8], v2[4][8];
    #pragma unroll
    for (int ks = 0; ks < 4; ks++)
        #pragma unroll
        for (int j = 0; j < 8; j++) { v[ks][j] = 0.f; v2[ks][j] = 0.f; }
    const int s = offs[arow], e = offs[arow + 1];
    int p = s;
    for (; p + 1 < e; p += 2) {
        const int c0 = csr[p], c1 = csr[p + 1];
        const float sc0 = norms[c0], sc1 = norms[c1];
        const float* q0 = xc_norm + (size_t)c0 * D + g * 8;
        const float* q1 = xc_norm + (size_t)c1 * D + g * 8;
        #pragma unroll
        for (int ks = 0; ks < 4; ks++) {
            float4 a = *(const float4*)(q0 + ks * 32), b = *(const float4*)(q0 + ks * 32 + 4);
            float4 x = *(const float4*)(q1 + ks * 32), y = *(const float4*)(q1 + ks * 32 + 4);
            v[ks][0] = fmaf(sc0, a.x, v[ks][0]);  v[ks][1] = fmaf(sc0, a.y, v[ks][1]);
            v[ks][2] = fmaf(sc0, a.z, v[ks][2]);  v[ks][3] = fmaf(sc0, a.w, v[ks][3]);
            v[ks][4] = fmaf(sc0, b.x, v[ks][4]);  v[ks][5] = fmaf(sc0, b.y, v[ks][5]);
            v[ks][6] = fmaf(sc0, b.z, v[ks][6]);  v[ks][7] = fmaf(sc0, b.w, v[ks][7]);
            v2[ks][0] = fmaf(sc1, x.x, v2[ks][0]); v2[ks][1] = fmaf(sc1, x.y, v2[ks][1]);
            v2[ks][2] = fmaf(sc1, x.z, v2[ks][2]); v2[ks][3] = fmaf(sc1, x.w, v2[ks][3]);
            v2[ks][4] = fmaf(sc1, y.x, v2[ks][4]); v2[ks][5] = fmaf(sc1, y.y, v2[ks][5]);
            v2[ks][6] = fmaf(sc1, y.z, v2[ks][6]); v2[ks][7] = fmaf(sc1, y.w, v2[ks][7]);
        }
    }
    if (p < e) {
        const int c0 = csr[p];
        const float sc0 = norms[c0];
        const float* q0 = xc_norm + (size_t)c0 * D + g * 8;
        #pragma unroll
        for (int ks = 0; ks < 4; ks++) {
            float4 a = *(const float4*)(q0 + ks * 32), b = *(const float4*)(q0 + ks * 32 + 4);
            v[ks][0] = fmaf(sc0, a.x, v[ks][0]); v[ks][1] = fmaf(sc0, a.y, v[ks][1]);
            v[ks][2] = fmaf(sc0, a.z, v[ks][2]); v[ks][3] = fmaf(sc0, a.w, v[ks][3]);
            v[ks][4] = fmaf(sc0, b.x, v[ks][4]); v[ks][5] = fmaf(sc0, b.y, v[ks][5]);
            v[ks][6] = fmaf(sc0, b.z, v[ks][6]); v[ks][7] = fmaf(sc0, b.w, v[ks][7]);
        }
    }
    #pragma unroll
    for (int ks = 0; ks < 4; ks++)
        #pragma unroll
        for (int j = 0; j < 8; j++) v[ks][j] += v2[ks][j];

    // issue hidden loads; they land during the msg MFMA block
    const float* rh = xl + (size_t)arow * D + g * 8;
    float vh[4][8];
    #pragma unroll
    for (int ks = 0; ks < 4; ks++) {
        float4 a = *(const float4*)(rh + ks * 32), b = *(const float4*)(rh + ks * 32 + 4);
        vh[ks][0] = a.x; vh[ks][1] = a.y; vh[ks][2] = a.z; vh[ks][3] = a.w;
        vh[ks][4] = b.x; vh[ks][5] = b.y; vh[ks][6] = b.z; vh[ks][7] = b.w;
    }
    #pragma unroll
    for (int ks = 0; ks < 4; ks++) {
        short8v ah, al;
        cvt_frag(v[ks], ah, al);
        #pragma unroll
        for (int n = 0; n < 8; n++) mm3(acc[n], ah, al, ih_hi, ih_lo, ((n * 8 + ks) * 64 + lane) * 8);
    }

    // issue flip loads; they land during the hidden MFMA block
    const float* rf = xl + (size_t)(arow ^ 256) * D + g * 8;
    float vf[4][8];
    #pragma unroll
    for (int ks = 0; ks < 4; ks++) {
        float4 a = *(const float4*)(rf + ks * 32), b = *(const float4*)(rf + ks * 32 + 4);
        vf[ks][0] = a.x; vf[ks][1] = a.y; vf[ks][2] = a.z; vf[ks][3] = a.w;
        vf[ks][4] = b.x; vf[ks][5] = b.y; vf[ks][6] = b.z; vf[ks][7] = b.w;
    }
    #pragma unroll
    for (int ks = 0; ks < 4; ks++) {
        short8v ah, al;
        cvt_frag(vh[ks], ah, al);
        #pragma unroll
        for (int n = 0; n < 8; n++) mm3(acc[n], ah, al, hh_hi, hh_lo, ((n * 4 + ks) * 64 + lane) * 8);
    }
    #pragma unroll
    for (int ks = 0; ks < 4; ks++) {
        short8v ah, al;
        cvt_frag(vf[ks], ah, al);
        #pragma unroll
        for (int n = 0; n < 8; n++) mm3(acc[n], ah, al, ih_hi, ih_lo, ((n * 8 + ks + 4) * 64 + lane) * 8);
    }

    float bias[8];
    #pragma unroll
    for (int n = 0; n < 8; n++) bias[n] = bih[n * 16 + m] + bhh[n * 16 + m];
    const float vb0 = vote ? vb[0] : 0.f;

    const int obase = blk * 64 + wid * 16 + g * 4;
    #pragma unroll
    for (int r = 0; r < 4; r++) {
        float w[8], ss = 0.f;
        #pragma unroll
        for (int n = 0; n < 8; n++) { w[n] = ftanh(acc[n][r] + bias[n]); ss += w[n] * w[n]; }
        ss += __shfl_xor(ss, 1); ss += __shfl_xor(ss, 2);
        ss += __shfl_xor(ss, 4); ss += __shfl_xor(ss, 8);
        const float rn = __builtin_amdgcn_rsqf(ss);
        const size_t rowoff = (size_t)(obase + r) * D + m;
        float td = 0.f, vd = 0.f;
        #pragma unroll
        for (int n = 0; n < 8; n++) {
            const float y = w[n] * rn;
            xl_out[rowoff + n * 16] = y;
            td += y * tv[n * 16 + m];
        }
        if (vote) {
            #pragma unroll
            for (int n = 0; n < 8; n++) vd += (w[n] * rn) * vw[n * 16 + m];
            vd += __shfl_xor(vd, 1); vd += __shfl_xor(vd, 2);
            vd += __shfl_xor(vd, 4); vd += __shfl_xor(vd, 8);
        }
        td += __shfl_xor(td, 1); td += __shfl_xor(td, 2);
        td += __shfl_xor(td, 4); td += __shfl_xor(td, 8);
        if (m == 0) {
            truth[obase + r] = td;
            if (truth2) truth2[obase + r] = td;
            if (vote) vote[obase + r] = vd + vb0;
        }
    }
}

// ---------------- mean-pool --------------------------------------------------
__global__ void pool_kernel(const float* __restrict__ votes, float* __restrict__ pool) {
    __shared__ float s[4];
    int g = blockIdx.x, t = threadIdx.x;
    float v = votes[g * LITS_PER + t] + votes[g * LITS_PER + 256 + t];
    #pragma unroll
    for (int m = 32; m; m >>= 1) v += __shfl_xor(v, m);
    if ((t & 63) == 0) s[t >> 6] = v;
    __syncthreads();
    if (t == 0) pool[g] = (s[0] + s[1] + s[2] + s[3]) * (1.0f / LITS_PER);
}

// ---------------- launch ----------------------------------------------------
extern "C" void kernel_launch(void* const* d_in, const int* in_sizes, int n_in,
                              void* d_out, int out_size, void* d_ws, size_t ws_size,
                              hipStream_t stream) {
    const int*   edge_lit = (const int*)d_in[1];
    const float* x_l0     = (const float*)d_in[2];
    const float* x_c0     = (const float*)d_in[3];
    const float* W_ih_lc  = (const float*)d_in[4];
    const float* W_hh_lc  = (const float*)d_in[5];
    const float* b_ih_lc  = (const float*)d_in[6];
    const float* b_hh_lc  = (const float*)d_in[7];
    const float* W_ih_cl  = (const float*)d_in[8];
    const float* W_hh_cl  = (const float*)d_in[9];
    const float* b_ih_cl  = (const float*)d_in[10];
    const float* b_hh_cl  = (const float*)d_in[11];
    const float* L_vote_w = (const float*)d_in[12];
    const float* L_vote_b = (const float*)d_in[13];
    const float* true_vec = (const float*)d_in[14];
    // d_in[15] = num_iters (=8, compile-time T)

    float* out   = (float*)d_out;
    float* xl_o  = out + OFF_XL;    // x_l state (even-t target, final)
    float* call  = out + OFF_CALL;  // x_c normalized states (output slices)
    float* tall  = out + OFF_TALL;

    // workspace
    float* norms  = (float*)d_ws;                         // NC (per-row pre-norm scale)
    float* xl_ws  = norms + NC;                           // NL*D (odd-t x_l)
    unsigned short* pk = (unsigned short*)(xl_ws + (size_t)NL * D);  // PK_TOT
    int* counts = (int*)(pk + PK_TOT);
    int* offs   = counts + NL;
    int* cursor = offs + NL + 1;
    int* csr    = cursor + NL;

    pack_all<<<(3 * PK_DD + PK_D2) / 256, 256, 0, stream>>>(W_ih_lc, W_hh_lc, W_hh_cl,
                                                            W_ih_cl, pk);

    // CSR (deterministic after per-row sort)
    hipMemsetAsync(counts, 0, NL * sizeof(int), stream);
    csr_count<<<NE / 256, 256, 0, stream>>>(edge_lit, counts);
    csr_scan<<<1, 1024, 0, stream>>>(counts, offs, cursor);
    csr_fill<<<NE / 256, 256, 0, stream>>>(edge_lit, cursor, csr);
    csr_sort<<<NL / 256, 256, 0, stream>>>(offs, csr);

    // init: normalize + truth0 + clause0
    rownorm_dot<<<NL / 4, 256, 0, stream>>>(x_l0, xl_o, true_vec, tall, out + OFF_T0, NL);
    rownorm_dot<<<NC / 4, 256, 0, stream>>>(x_c0, call, nullptr, nullptr, nullptr, NC);

    for (int t = 1; t <= T; t++) {
        const float* xl_src = (t & 1) ? xl_o : xl_ws;   // ping-pong; T even ends in xl_o
        float*       xl_dst = (t & 1) ? xl_ws : xl_o;
        lc_mfma<<<NC / 64, 256, 0, stream>>>(
            edge_lit, xl_src, call + (size_t)(t - 1) * NC * D, pk,
            b_ih_lc, b_hh_lc, call + (size_t)t * NC * D, norms);
        cl_mfma<<<NL / 64, 256, 0, stream>>>(
            offs, csr, call + (size_t)t * NC * D, norms, xl_src, pk,
            b_ih_cl, b_hh_cl, true_vec, L_vote_w, L_vote_b,
            xl_dst, tall + (size_t)t * NL,
            (t == T) ? out + OFF_TLAST : nullptr,
            (t == T) ? out + OFF_VOTE : nullptr);
    }

    pool_kernel<<<Bg, 256, 0, stream>>>(out + OFF_VOTE, out + OFF_POOL);
}

// Round 6
// 753.317 us; speedup vs baseline: 1.3053x; 1.3053x over previous
//
#include <hip/hip_runtime.h>
#include <math.h>

// NeuroSAT RNN forward on MI355X — MFMA bf16x3, weights staged in LDS,
// whole grid resident (256 blocks = 1 block/CU).
namespace {
constexpr int NVARS    = 256;
constexpr int LITS_PER = 2 * NVARS;     // 512
constexpr int Bg       = 64;            // graphs
constexpr int NL       = Bg * LITS_PER; // 32768 literals
constexpr int CLS_PER  = 1024;
constexpr int NC       = Bg * CLS_PER;  // 65536 clauses
constexpr int NE       = NC * 3;        // 196608 edges (K=3)
constexpr int D        = 128;
constexpr int T        = 8;             // num_iters (fixed scalar input)

// d_out flat layout (reference tuple order)
constexpr size_t OFF_VOTE  = 0;                                  // [NL]
constexpr size_t OFF_XL    = (size_t)NL;                         // [NL*D]   (x_l state)
constexpr size_t OFF_POOL  = OFF_XL + (size_t)NL * D;            // [Bg]
constexpr size_t OFF_TLAST = OFF_POOL + Bg;                      // [NL]
constexpr size_t OFF_TALL  = OFF_TLAST + NL;                     // [(T+1)*NL]
constexpr size_t OFF_CALL  = OFF_TALL + (size_t)(T + 1) * NL;    // [(T+1)*NC*D] (x_c state)
constexpr size_t OFF_T0    = OFF_CALL + (size_t)(T + 1) * NC * D;// [NL]

// packed weights: 5 logical DxD matrices, each hi plane (16384 us) + lo plane:
// 0: W_ih_lc | 1: W_hh_lc | 2: W_hh_cl | 3: W_ih_cl[:, :128] | 4: W_ih_cl[:, 128:]
constexpr int PKM    = 16384;           // ushorts per plane (128x128 frag-packed)
constexpr int PK_TOT = 5 * 2 * PKM;     // 163840 ushorts
} // namespace

typedef __attribute__((ext_vector_type(8))) short short8v;  // 8 bf16 (4 VGPRs)
typedef __attribute__((ext_vector_type(4))) float f32x4;

__device__ __forceinline__ unsigned short f2bf(float v) {
    unsigned u = __float_as_uint(v);
    return (unsigned short)((u + 0x7fffu + ((u >> 16) & 1u)) >> 16);  // RNE
}
__device__ __forceinline__ float bf2f(unsigned short b) {
    return __uint_as_float(((unsigned)b) << 16);
}
__device__ __forceinline__ void cvt_frag(const float (&v)[8], short8v& ah, short8v& al) {
    #pragma unroll
    for (int j = 0; j < 8; j++) {
        unsigned short h = f2bf(v[j]);
        ah[j] = (short)h;
        al[j] = (short)f2bf(v[j] - bf2f(h));
    }
}
// fast tanh: 1 - 2/(2^(2x*log2e)+1)
__device__ __forceinline__ float ftanh(float x) {
    float e = __builtin_amdgcn_exp2f(x * 2.885390081777926814f);
    return 1.0f - 2.0f * __builtin_amdgcn_rcpf(e + 1.0f);
}

// bf16x3 dual-rowgroup MFMA site: B (hi+lo) from LDS, 6 MFMAs
__device__ __forceinline__ void mm3l(f32x4& c0, f32x4& c1,
                                     short8v a0h, short8v a0l, short8v a1h, short8v a1l,
                                     const unsigned short* buf, int off) {
    short8v bh = *(const short8v*)(buf + off);
    short8v bl = *(const short8v*)(buf + PKM + off);
    c0 = __builtin_amdgcn_mfma_f32_16x16x32_bf16(a0h, bh, c0, 0, 0, 0);
    c0 = __builtin_amdgcn_mfma_f32_16x16x32_bf16(a0h, bl, c0, 0, 0, 0);
    c0 = __builtin_amdgcn_mfma_f32_16x16x32_bf16(a0l, bh, c0, 0, 0, 0);
    c1 = __builtin_amdgcn_mfma_f32_16x16x32_bf16(a1h, bh, c1, 0, 0, 0);
    c1 = __builtin_amdgcn_mfma_f32_16x16x32_bf16(a1h, bl, c1, 0, 0, 0);
    c1 = __builtin_amdgcn_mfma_f32_16x16x32_bf16(a1l, bh, c1, 0, 0, 0);
}

// ---------------- W packing --------------------------------------------------
__global__ __launch_bounds__(256) void pack5(
    const float* __restrict__ ihlc, const float* __restrict__ hhlc,
    const float* __restrict__ hhcl, const float* __restrict__ ihcl,
    unsigned short* __restrict__ pk) {
    int idx = blockIdx.x * 256 + threadIdx.x;      // 5*16384 total
    int mat = idx >> 14, rel = idx & 16383;
    int j = rel & 7, lane = (rel >> 3) & 63, ks = (rel >> 9) & 3, n = rel >> 11;
    int r = n * 16 + (lane & 15);
    int k = ks * 32 + (lane >> 4) * 8 + j;
    float w;
    if (mat == 0)      w = ihlc[r * 128 + k];
    else if (mat == 1) w = hhlc[r * 128 + k];
    else if (mat == 2) w = hhcl[r * 128 + k];
    else if (mat == 3) w = ihcl[r * 256 + k];
    else               w = ihcl[r * 256 + 128 + k];
    unsigned short h = f2bf(w);
    pk[mat * 2 * PKM + rel] = h;
    pk[mat * 2 * PKM + PKM + rel] = f2bf(w - bf2f(h));
}

// ---------------- CSR build --------------------------------------------------
__global__ void csr_count(const int* __restrict__ edge_lit, int* __restrict__ counts) {
    int e = blockIdx.x * blockDim.x + threadIdx.x;
    if (e < NE) atomicAdd(&counts[edge_lit[e]], 1);
}

__global__ __launch_bounds__(1024) void csr_scan(const int* __restrict__ counts,
                                                 int* __restrict__ offs,
                                                 int* __restrict__ cursor) {
    __shared__ int part[1024];
    const int t = threadIdx.x;
    const int base = t * 32;
    int local[32];
    int s = 0;
    for (int i = 0; i < 32; i++) { local[i] = s; s += counts[base + i]; }
    part[t] = s;
    __syncthreads();
    for (int d = 1; d < 1024; d <<= 1) {
        int v = 0;
        if (t >= d) v = part[t - d];
        __syncthreads();
        if (t >= d) part[t] += v;
        __syncthreads();
    }
    const int excl = (t == 0) ? 0 : part[t - 1];
    for (int i = 0; i < 32; i++) {
        int o = excl + local[i];
        offs[base + i] = o;
        cursor[base + i] = o;
    }
    if (t == 1023) offs[NL] = part[1023];
}

__global__ void csr_fill(const int* __restrict__ edge_lit, int* __restrict__ cursor,
                         int* __restrict__ csr) {
    int e = blockIdx.x * blockDim.x + threadIdx.x;
    if (e < NE) {
        int l = edge_lit[e];
        int p = atomicAdd(&cursor[l], 1);
        csr[p] = e / 3;
    }
}

__global__ void csr_sort(const int* __restrict__ offs, int* __restrict__ csr) {
    int l = blockIdx.x * blockDim.x + threadIdx.x;
    if (l >= NL) return;
    int s = offs[l], e = offs[l + 1];
    for (int i = s + 1; i < e; i++) {
        int v = csr[i];
        int j = i - 1;
        while (j >= s && csr[j] > v) { csr[j + 1] = csr[j]; j--; }
        csr[j + 1] = v;
    }
}

// ---------------- init: row L2-normalize (+ fused dot) -----------------------
__global__ void rownorm_dot(const float* __restrict__ in, float* __restrict__ out,
                            const float* __restrict__ dotw, float* __restrict__ dot0,
                            float* __restrict__ dot1, int nrows) {
    int wave = (int)((blockIdx.x * blockDim.x + threadIdx.x) >> 6);
    int lane = threadIdx.x & 63;
    if (wave >= nrows) return;
    const float* r = in + (size_t)wave * D;
    float v0 = r[lane], v1 = r[lane + 64];
    float ss = v0 * v0 + v1 * v1;
    #pragma unroll
    for (int m = 32; m; m >>= 1) ss += __shfl_xor(ss, m);
    float rn = 1.0f / sqrtf(ss);
    float y0 = v0 * rn, y1 = v1 * rn;
    float* o = out + (size_t)wave * D;
    o[lane] = y0;
    o[lane + 64] = y1;
    if (dotw) {
        float dv = y0 * dotw[lane] + y1 * dotw[lane + 64];
        #pragma unroll
        for (int m = 32; m; m >>= 1) dv += __shfl_xor(dv, m);
        if (lane == 0) {
            dot0[wave] = dv;
            if (dot1) dot1[wave] = dv;
        }
    }
}

// -------- gather helpers -----------------------------------------------------
__device__ __forceinline__ void gather3(const int* __restrict__ ep,
                                        const float* __restrict__ xl, int arow, int g,
                                        float (&v)[4][8]) {
    int e0 = ep[3 * arow], e1 = ep[3 * arow + 1], e2 = ep[3 * arow + 2];
    const float* r0 = xl + (size_t)e0 * D + g * 8;
    const float* r1 = xl + (size_t)e1 * D + g * 8;
    const float* r2 = xl + (size_t)e2 * D + g * 8;
    #pragma unroll
    for (int ks = 0; ks < 4; ks++) {
        float4 a0 = *(const float4*)(r0 + ks * 32), a1 = *(const float4*)(r0 + ks * 32 + 4);
        float4 b0 = *(const float4*)(r1 + ks * 32), b1 = *(const float4*)(r1 + ks * 32 + 4);
        float4 c0 = *(const float4*)(r2 + ks * 32), c1 = *(const float4*)(r2 + ks * 32 + 4);
        v[ks][0] = a0.x + b0.x + c0.x; v[ks][1] = a0.y + b0.y + c0.y;
        v[ks][2] = a0.z + b0.z + c0.z; v[ks][3] = a0.w + b0.w + c0.w;
        v[ks][4] = a1.x + b1.x + c1.x; v[ks][5] = a1.y + b1.y + c1.y;
        v[ks][6] = a1.z + b1.z + c1.z; v[ks][7] = a1.w + b1.w + c1.w;
    }
}

__device__ __forceinline__ void loadrow(const float* __restrict__ rp, float (&v)[4][8]) {
    #pragma unroll
    for (int ks = 0; ks < 4; ks++) {
        float4 a = *(const float4*)(rp + ks * 32), b = *(const float4*)(rp + ks * 32 + 4);
        v[ks][0] = a.x; v[ks][1] = a.y; v[ks][2] = a.z; v[ks][3] = a.w;
        v[ks][4] = b.x; v[ks][5] = b.y; v[ks][6] = b.z; v[ks][7] = b.w;
    }
}

__device__ __forceinline__ void gatherCSR(const int* __restrict__ offs,
                                          const int* __restrict__ csr,
                                          const float* __restrict__ xcn,
                                          const float* __restrict__ norms,
                                          int arow, int g, float (&v)[4][8]) {
    #pragma unroll
    for (int ks = 0; ks < 4; ks++)
        #pragma unroll
        for (int j = 0; j < 8; j++) v[ks][j] = 0.f;
    const int s = offs[arow], e = offs[arow + 1];
    for (int p = s; p < e; p++) {
        const int c = csr[p];
        const float sc = norms[c];
        const float* q = xcn + (size_t)c * D + g * 8;
        #pragma unroll
        for (int ks = 0; ks < 4; ks++) {
            float4 a = *(const float4*)(q + ks * 32), b = *(const float4*)(q + ks * 32 + 4);
            v[ks][0] = fmaf(sc, a.x, v[ks][0]); v[ks][1] = fmaf(sc, a.y, v[ks][1]);
            v[ks][2] = fmaf(sc, a.z, v[ks][2]); v[ks][3] = fmaf(sc, a.w, v[ks][3]);
            v[ks][4] = fmaf(sc, b.x, v[ks][4]); v[ks][5] = fmaf(sc, b.y, v[ks][5]);
            v[ks][6] = fmaf(sc, b.z, v[ks][6]); v[ks][7] = fmaf(sc, b.w, v[ks][7]);
        }
    }
}

// ---------------- LC: 256 blocks x 512 thr; 256 rows/block; W in LDS ---------
__global__ __launch_bounds__(512, 2) void lc_mfma(
    const int* __restrict__ edge_lit, const float* __restrict__ xl,
    const float* __restrict__ xc_prev, const unsigned short* __restrict__ pk,
    const float* __restrict__ bih, const float* __restrict__ bhh,
    float* __restrict__ xc_norm, float* __restrict__ norms) {
    extern __shared__ __align__(16) unsigned short lds[];  // [0,2*PKM)=ih hi/lo, [2*PKM,4*PKM)=hh
    const int tid = threadIdx.x, wid = tid >> 6, lane = tid & 63;
    const int m = lane & 15, g = lane >> 4;
    const int p = blockIdx.x;
    const int blk = (p & 7) * 32 + (p >> 3);    // XCD-chunked, grid=256 bijective
    const int rowbase = blk * 256;
    const int arow0 = rowbase + wid * 32 + m, arow1 = arow0 + 16;

    // stage ih+hh (128 KB, contiguous in pk)
    {
        const short8v* src = (const short8v*)pk;
        short8v* dst = (short8v*)lds;
        #pragma unroll
        for (int i = 0; i < 16; i++) dst[i * 512 + tid] = src[i * 512 + tid];
    }
    // gathers (overlap with stage)
    float v0[4][8], v1[4][8];
    gather3(edge_lit, xl, arow0, g, v0);
    gather3(edge_lit, xl, arow1, g, v1);
    __syncthreads();

    short8v a0h[4], a0l[4], a1h[4], a1l[4];
    #pragma unroll
    for (int ks = 0; ks < 4; ks++) { cvt_frag(v0[ks], a0h[ks], a0l[ks]); cvt_frag(v1[ks], a1h[ks], a1l[ks]); }

    f32x4 acc0[8], acc1[8];
    #pragma unroll
    for (int n = 0; n < 8; n++) { acc0[n] = (f32x4)0.f; acc1[n] = (f32x4)0.f; }

    // issue hidden loads; land under msg MFMAs
    float vh0[4][8], vh1[4][8];
    loadrow(xc_prev + (size_t)arow0 * D + g * 8, vh0);
    loadrow(xc_prev + (size_t)arow1 * D + g * 8, vh1);

    #pragma unroll
    for (int ks = 0; ks < 4; ks++)
        #pragma unroll
        for (int n = 0; n < 8; n++)
            mm3l(acc0[n], acc1[n], a0h[ks], a0l[ks], a1h[ks], a1l[ks],
                 lds, ((n * 4 + ks) * 64 + lane) * 8);

    #pragma unroll
    for (int ks = 0; ks < 4; ks++) { cvt_frag(vh0[ks], a0h[ks], a0l[ks]); cvt_frag(vh1[ks], a1h[ks], a1l[ks]); }
    #pragma unroll
    for (int ks = 0; ks < 4; ks++)
        #pragma unroll
        for (int n = 0; n < 8; n++)
            mm3l(acc0[n], acc1[n], a0h[ks], a0l[ks], a1h[ks], a1l[ks],
                 lds + 2 * PKM, ((n * 4 + ks) * 64 + lane) * 8);

    float bias[8];
    #pragma unroll
    for (int n = 0; n < 8; n++) bias[n] = bih[n * 16 + m] + bhh[n * 16 + m];

    #pragma unroll
    for (int rg = 0; rg < 2; rg++) {
        const int obase = rowbase + wid * 32 + rg * 16 + g * 4;
        #pragma unroll
        for (int r = 0; r < 4; r++) {
            float w[8], ss = 0.f;
            #pragma unroll
            for (int n = 0; n < 8; n++) {
                float a = rg ? acc1[n][r] : acc0[n][r];
                w[n] = ftanh(a + bias[n]); ss += w[n] * w[n];
            }
            ss += __shfl_xor(ss, 1); ss += __shfl_xor(ss, 2);
            ss += __shfl_xor(ss, 4); ss += __shfl_xor(ss, 8);
            const float rn = __builtin_amdgcn_rsqf(ss);
            const size_t rowoff = (size_t)(obase + r) * D + m;
            #pragma unroll
            for (int n = 0; n < 8; n++) xc_norm[rowoff + n * 16] = w[n] * rn;
            if (m == 0) norms[obase + r] = ss * rn;   // ||row||
        }
    }
}

// ---------------- CL: 256 blocks x 512 thr; 128 rows x N-split; W in LDS -----
__global__ __launch_bounds__(512, 2) void cl_mfma(
    const int* __restrict__ offs, const int* __restrict__ csr,
    const float* __restrict__ xc_norm, const float* __restrict__ norms,
    const float* __restrict__ xl, const unsigned short* __restrict__ pk,
    const float* __restrict__ bih, const float* __restrict__ bhh,
    const float* __restrict__ tv, const float* __restrict__ vw,
    const float* __restrict__ vb,
    float* __restrict__ xl_out, float* __restrict__ truth,
    float* __restrict__ truth2, float* __restrict__ vote) {
    extern __shared__ __align__(16) unsigned short lds[];
    // bufA [0,2*PKM): ih_msg -> later ih_flip ; bufB [2*PKM,4*PKM): hh
    float* sc = (float*)(lds + 4 * PKM);   // scratch: ssx[128][2], twx[128][2], vwx[128][2]
    float* ssx = sc, * twx = sc + 256, * vwx = sc + 512;

    const int tid = threadIdx.x, wid = tid >> 6, lane = tid & 63;
    const int m = lane & 15, g = lane >> 4;
    const int rg = wid >> 1, nh = wid & 1, nbase = nh * 4;
    const int p0 = blockIdx.x;
    const int blk = (p0 & 7) * 32 + (p0 >> 3);
    const int rowbase = blk * 128;
    const int arow0 = rowbase + rg * 32 + m, arow1 = arow0 + 16;

    // stage bufA=ih_msg, bufB=hh
    {
        const short8v* srcA = (const short8v*)(pk + 3 * 2 * PKM);  // mat3
        const short8v* srcB = (const short8v*)(pk + 2 * 2 * PKM);  // mat2
        short8v* dA = (short8v*)lds;
        short8v* dB = (short8v*)(lds + 2 * PKM);
        #pragma unroll
        for (int i = 0; i < 8; i++) dA[i * 512 + tid] = srcA[i * 512 + tid];
        #pragma unroll
        for (int i = 0; i < 8; i++) dB[i * 512 + tid] = srcB[i * 512 + tid];
    }
    // msg gathers (overlap with stage)
    float v0[4][8], v1[4][8];
    gatherCSR(offs, csr, xc_norm, norms, arow0, g, v0);
    gatherCSR(offs, csr, xc_norm, norms, arow1, g, v1);
    __syncthreads();                                   // b1

    short8v a0h[4], a0l[4], a1h[4], a1l[4];
    #pragma unroll
    for (int ks = 0; ks < 4; ks++) { cvt_frag(v0[ks], a0h[ks], a0l[ks]); cvt_frag(v1[ks], a1h[ks], a1l[ks]); }

    f32x4 acc0[4], acc1[4];
    #pragma unroll
    for (int n = 0; n < 4; n++) { acc0[n] = (f32x4)0.f; acc1[n] = (f32x4)0.f; }

    // T14 split: issue flip-restage + hidden loads before msg MFMAs
    short8v fr[8];
    {
        const short8v* srcF = (const short8v*)(pk + 4 * 2 * PKM);  // mat4 = ih_flip
        #pragma unroll
        for (int i = 0; i < 8; i++) fr[i] = srcF[i * 512 + tid];
    }
    float vh0[4][8], vh1[4][8];
    loadrow(xl + (size_t)arow0 * D + g * 8, vh0);
    loadrow(xl + (size_t)arow1 * D + g * 8, vh1);

    #pragma unroll
    for (int ks = 0; ks < 4; ks++)
        #pragma unroll
        for (int nn = 0; nn < 4; nn++)
            mm3l(acc0[nn], acc1[nn], a0h[ks], a0l[ks], a1h[ks], a1l[ks],
                 lds, (((nbase + nn) * 4 + ks) * 64 + lane) * 8);

    __syncthreads();                                   // b2: all msg reads of bufA done
    {
        short8v* dA = (short8v*)lds;
        #pragma unroll
        for (int i = 0; i < 8; i++) dA[i * 512 + tid] = fr[i];
    }
    #pragma unroll
    for (int ks = 0; ks < 4; ks++) { cvt_frag(vh0[ks], a0h[ks], a0l[ks]); cvt_frag(vh1[ks], a1h[ks], a1l[ks]); }

    // issue flip-row loads; land under hidden MFMAs
    float vf0[4][8], vf1[4][8];
    loadrow(xl + (size_t)(arow0 ^ 256) * D + g * 8, vf0);
    loadrow(xl + (size_t)(arow1 ^ 256) * D + g * 8, vf1);

    #pragma unroll
    for (int ks = 0; ks < 4; ks++)
        #pragma unroll
        for (int nn = 0; nn < 4; nn++)
            mm3l(acc0[nn], acc1[nn], a0h[ks], a0l[ks], a1h[ks], a1l[ks],
                 lds + 2 * PKM, (((nbase + nn) * 4 + ks) * 64 + lane) * 8);

    __syncthreads();                                   // b3: flip staged & visible
    #pragma unroll
    for (int ks = 0; ks < 4; ks++) { cvt_frag(vf0[ks], a0h[ks], a0l[ks]); cvt_frag(vf1[ks], a1h[ks], a1l[ks]); }
    #pragma unroll
    for (int ks = 0; ks < 4; ks++)
        #pragma unroll
        for (int nn = 0; nn < 4; nn++)
            mm3l(acc0[nn], acc1[nn], a0h[ks], a0l[ks], a1h[ks], a1l[ks],
                 lds, (((nbase + nn) * 4 + ks) * 64 + lane) * 8);

    // epilogue: partial tanh/ss/dots, cross-wave (nh) combine via LDS
    float bias[4], tvv[4], vwv[4];
    #pragma unroll
    for (int nn = 0; nn < 4; nn++) {
        int n = nbase + nn;
        bias[nn] = bih[n * 16 + m] + bhh[n * 16 + m];
        tvv[nn] = tv[n * 16 + m];
        vwv[nn] = vote ? vw[n * 16 + m] : 0.f;
    }
    float wv[2][4][4];
    #pragma unroll
    for (int rgi = 0; rgi < 2; rgi++) {
        #pragma unroll
        for (int r = 0; r < 4; r++) {
            float ssp = 0.f, twp = 0.f, vwp = 0.f;
            #pragma unroll
            for (int nn = 0; nn < 4; nn++) {
                float a = rgi ? acc1[nn][r] : acc0[nn][r];
                float w = ftanh(a + bias[nn]);
                wv[rgi][r][nn] = w;
                ssp += w * w; twp += w * tvv[nn]; vwp += w * vwv[nn];
            }
            ssp += __shfl_xor(ssp, 1); ssp += __shfl_xor(ssp, 2);
            ssp += __shfl_xor(ssp, 4); ssp += __shfl_xor(ssp, 8);
            twp += __shfl_xor(twp, 1); twp += __shfl_xor(twp, 2);
            twp += __shfl_xor(twp, 4); twp += __shfl_xor(twp, 8);
            if (vote) {
                vwp += __shfl_xor(vwp, 1); vwp += __shfl_xor(vwp, 2);
                vwp += __shfl_xor(vwp, 4); vwp += __shfl_xor(vwp, 8);
            }
            if (m == 0) {
                int rl = rg * 32 + rgi * 16 + g * 4 + r;
                ssx[rl * 2 + nh] = ssp;
                twx[rl * 2 + nh] = twp;
                if (vote) vwx[rl * 2 + nh] = vwp;
            }
        }
    }
    __syncthreads();                                   // b4
    const float vb0 = vote ? vb[0] : 0.f;
    #pragma unroll
    for (int rgi = 0; rgi < 2; rgi++) {
        #pragma unroll
        for (int r = 0; r < 4; r++) {
            const int rl = rg * 32 + rgi * 16 + g * 4 + r;
            const int grow = rowbase + rl;
            const float ss = ssx[rl * 2] + ssx[rl * 2 + 1];
            const float rn = __builtin_amdgcn_rsqf(ss);
            const size_t rowoff = (size_t)grow * D + m;
            #pragma unroll
            for (int nn = 0; nn < 4; nn++)
                xl_out[rowoff + (nbase + nn) * 16] = wv[rgi][r][nn] * rn;
            if (m == 0 && nh == 0) {
                const float td = rn * (twx[rl * 2] + twx[rl * 2 + 1]);
                truth[grow] = td;
                if (truth2) truth2[grow] = td;
                if (vote) vote[grow] = rn * (vwx[rl * 2] + vwx[rl * 2 + 1]) + vb0;
            }
        }
    }
}

// ---------------- mean-pool --------------------------------------------------
__global__ void pool_kernel(const float* __restrict__ votes, float* __restrict__ pool) {
    __shared__ float s[4];
    int g = blockIdx.x, t = threadIdx.x;
    float v = votes[g * LITS_PER + t] + votes[g * LITS_PER + 256 + t];
    #pragma unroll
    for (int m = 32; m; m >>= 1) v += __shfl_xor(v, m);
    if ((t & 63) == 0) s[t >> 6] = v;
    __syncthreads();
    if (t == 0) pool[g] = (s[0] + s[1] + s[2] + s[3]) * (1.0f / LITS_PER);
}

// ---------------- launch ----------------------------------------------------
extern "C" void kernel_launch(void* const* d_in, const int* in_sizes, int n_in,
                              void* d_out, int out_size, void* d_ws, size_t ws_size,
                              hipStream_t stream) {
    const int*   edge_lit = (const int*)d_in[1];
    const float* x_l0     = (const float*)d_in[2];
    const float* x_c0     = (const float*)d_in[3];
    const float* W_ih_lc  = (const float*)d_in[4];
    const float* W_hh_lc  = (const float*)d_in[5];
    const float* b_ih_lc  = (const float*)d_in[6];
    const float* b_hh_lc  = (const float*)d_in[7];
    const float* W_ih_cl  = (const float*)d_in[8];
    const float* W_hh_cl  = (const float*)d_in[9];
    const float* b_ih_cl  = (const float*)d_in[10];
    const float* b_hh_cl  = (const float*)d_in[11];
    const float* L_vote_w = (const float*)d_in[12];
    const float* L_vote_b = (const float*)d_in[13];
    const float* true_vec = (const float*)d_in[14];
    // d_in[15] = num_iters (=8, compile-time T)

    float* out   = (float*)d_out;
    float* xl_o  = out + OFF_XL;    // x_l state (even-t target, final)
    float* call  = out + OFF_CALL;  // x_c normalized states (output slices)
    float* tall  = out + OFF_TALL;

    // workspace
    float* norms  = (float*)d_ws;                         // NC
    float* xl_ws  = norms + NC;                           // NL*D
    unsigned short* pk = (unsigned short*)(xl_ws + (size_t)NL * D);  // PK_TOT
    int* counts = (int*)(pk + PK_TOT);
    int* offs   = counts + NL;
    int* cursor = offs + NL + 1;
    int* csr    = cursor + NL;

    pack5<<<5 * PKM / 256, 256, 0, stream>>>(W_ih_lc, W_hh_lc, W_hh_cl, W_ih_cl, pk);

    // CSR (deterministic after per-row sort)
    hipMemsetAsync(counts, 0, NL * sizeof(int), stream);
    csr_count<<<NE / 256, 256, 0, stream>>>(edge_lit, counts);
    csr_scan<<<1, 1024, 0, stream>>>(counts, offs, cursor);
    csr_fill<<<NE / 256, 256, 0, stream>>>(edge_lit, cursor, csr);
    csr_sort<<<NL / 256, 256, 0, stream>>>(offs, csr);

    // init: normalize + truth0 + clause0
    rownorm_dot<<<NL / 4, 256, 0, stream>>>(x_l0, xl_o, true_vec, tall, out + OFF_T0, NL);
    rownorm_dot<<<NC / 4, 256, 0, stream>>>(x_c0, call, nullptr, nullptr, nullptr, NC);

    const size_t lcShm = 4 * PKM * sizeof(unsigned short);            // 128 KB
    const size_t clShm = 4 * PKM * sizeof(unsigned short) + 3072;     // 128 KB + scratch

    for (int t = 1; t <= T; t++) {
        const float* xl_src = (t & 1) ? xl_o : xl_ws;   // ping-pong; T even ends in xl_o
        float*       xl_dst = (t & 1) ? xl_ws : xl_o;
        lc_mfma<<<NC / 256, 512, lcShm, stream>>>(
            edge_lit, xl_src, call + (size_t)(t - 1) * NC * D, pk,
            b_ih_lc, b_hh_lc, call + (size_t)t * NC * D, norms);
        cl_mfma<<<NL / 128, 512, clShm, stream>>>(
            offs, csr, call + (size_t)t * NC * D, norms, xl_src, pk,
            b_ih_cl, b_hh_cl, true_vec, L_vote_w, L_vote_b,
            xl_dst, tall + (size_t)t * NL,
            (t == T) ? out + OFF_TLAST : nullptr,
            (t == T) ? out + OFF_VOTE : nullptr);
    }

    pool_kernel<<<Bg, 256, 0, stream>>>(out + OFF_VOTE, out + OFF_POOL);
}